// Round 1
// baseline (365.723 us; speedup 1.0000x reference)
//
#include <hip/hip_runtime.h>

// Problem geometry (fixed by reference):
//   inputs (8, 64, 16, 32, 32) fp32, embedding (512, 64) fp32
//   N = 8*16*32*32 = 131072 positions, D = 64, K = 512
//   d_out layout (fp32): [0, 8388608) quantized_st, [8388608] loss,
//                        [8388609, 8519681) indices (as float)
#define SPATIAL   16384      // 16*32*32
#define DIM       64
#define KCODES    512
#define NPOS      131072
#define QST_ELEMS 8388608
#define LOSS_OFF  8388608
#define IDX_OFF   8388609

// --- non-contractable fp32 ops (match numpy's plain mul/add/sub) ---
__device__ __forceinline__ float mul_rn(float a, float b) {
#pragma clang fp contract(off)
    return a * b;
}
__device__ __forceinline__ float add_rn(float a, float b) {
#pragma clang fp contract(off)
    return a + b;
}
__device__ __forceinline__ float sub_rn(float a, float b) {
#pragma clang fp contract(off)
    return a - b;
}

// numpy pairwise_sum for n=64 contiguous fp32: 8 accumulators striding by 8,
// then ((r0+r1)+(r2+r3))+((r4+r5)+(r6+r7)).  Input here: squares of v[].
__device__ __forceinline__ float np_sumsq64(const float* v) {
    float r[8];
#pragma unroll
    for (int j = 0; j < 8; ++j) r[j] = mul_rn(v[j], v[j]);
#pragma unroll
    for (int i = 8; i < 64; i += 8) {
#pragma unroll
        for (int j = 0; j < 8; ++j) r[j] = add_rn(r[j], mul_rn(v[i + j], v[i + j]));
    }
    return add_rn(add_rn(add_rn(r[0], r[1]), add_rn(r[2], r[3])),
                  add_rn(add_rn(r[4], r[5]), add_rn(r[6], r[7])));
}

// e2[k] = np.sum(embedding**2, axis=1), bit-exact numpy pairwise order
__global__ void vq_e2_kernel(const float* __restrict__ emb, float* __restrict__ e2) {
    int k = threadIdx.x;
    if (k >= KCODES) return;
    float v[DIM];
#pragma unroll
    for (int d = 0; d < DIM; ++d) v[d] = emb[k * DIM + d];
    e2[k] = np_sumsq64(v);
}

__global__ __launch_bounds__(256) void vq_main_kernel(
        const float* __restrict__ in, const float* __restrict__ emb,
        const float* __restrict__ e2, float* __restrict__ out,
        double* __restrict__ lossacc) {
    int p = blockIdx.x * 256 + threadIdx.x;   // position index (b,t,h,w) flat
    int b = p >> 14;                          // p / 16384
    int s = p & 16383;                        // spatial index within batch
    const float* xin = in + (size_t)b * (DIM * SPATIAL) + s;

    // load the 64-channel vector for this position (coalesced across lanes)
    float x[DIM];
#pragma unroll
    for (int d = 0; d < DIM; ++d) x[d] = xin[(size_t)d * SPATIAL];

    // x2 bit-exact vs numpy np.sum(flat**2, axis=1)
    float x2 = np_sumsq64(x);

    // distance scan: d_k = fl(fl(x2 + e2[k]) - 2*dot), dot = serial-K fp32 FMA
    // (matches BLAS sgemm micro-kernel accumulation). argmin = first strict min.
    float best = __builtin_inff();
    int bidx = 0;
#pragma unroll 2
    for (int k = 0; k < KCODES; ++k) {
        const float* ek = emb + k * DIM;      // wave-uniform -> s_load
        float acc = 0.0f;
#pragma unroll
        for (int d = 0; d < DIM; ++d) acc = __builtin_fmaf(x[d], ek[d], acc);
        float t1, dist;
        {
#pragma clang fp contract(off)
            t1 = x2 + e2[k];
            dist = t1 - 2.0f * acc;           // 2.0f*acc exact (power of 2)
        }
        if (dist < best) { best = dist; bidx = k; }
    }

    // outputs
    out[IDX_OFF + p] = (float)bidx;

    const float* eq = emb + bidx * DIM;       // divergent gather (L2-resident)
    float* oq = out + (size_t)b * (DIM * SPATIAL) + s;
    double lsum = 0.0;
#pragma unroll
    for (int d = 0; d < DIM; ++d) {
        float q = eq[d];
        float diff = sub_rn(q, x[d]);         // fl(q - x)
        float qst = add_rn(x[d], diff);       // fl(x + fl(q - x))  (straight-through)
        oq[(size_t)d * SPATIAL] = qst;
        float sq = mul_rn(diff, diff);
        lsum += (double)sq;
    }

    // wave64 reduce then one atomic per wave
#pragma unroll
    for (int off = 32; off > 0; off >>= 1) lsum += __shfl_down(lsum, off, 64);
    if ((threadIdx.x & 63) == 0) atomicAdd(lossacc, lsum);
}

__global__ void vq_finalize_kernel(const double* __restrict__ acc,
                                   float* __restrict__ out) {
    double m = *acc / (double)QST_ELEMS;
    float mf = (float)m;
    // loss = q_latent + 0.25*e_latent, both equal mf in value
    out[LOSS_OFF] = add_rn(mf, mul_rn(0.25f, mf));
}

extern "C" void kernel_launch(void* const* d_in, const int* in_sizes, int n_in,
                              void* d_out, int out_size, void* d_ws, size_t ws_size,
                              hipStream_t stream) {
    const float* in  = (const float*)d_in[0];
    const float* emb = (const float*)d_in[1];
    float* out = (float*)d_out;
    float* e2 = (float*)d_ws;                          // 512 floats = 2048 B
    double* lossacc = (double*)((char*)d_ws + 2048);   // 8 B, aligned

    hipMemsetAsync(lossacc, 0, sizeof(double), stream);
    vq_e2_kernel<<<1, KCODES, 0, stream>>>(emb, e2);
    vq_main_kernel<<<NPOS / 256, 256, 0, stream>>>(in, emb, e2, out, lossacc);
    vq_finalize_kernel<<<1, 1, 0, stream>>>(lossacc, out);
}